// Round 1
// baseline (179.565 us; speedup 1.0000x reference)
//
#include <hip/hip_runtime.h>

#define NN 100000
#define NE 3200000
#define HC 16

#define BKT_BITS 7
#define BKT_NODES 128                 // nodes per bucket
#define NB 782                        // ceil(NN / 128) buckets
#define CHUNK_S 8192                  // edges per bin block
#define NCH 391                       // ceil(NE / CHUNK_S)
#define MCAP 5120                     // per-bucket region capacity (max bucket ~4350)

typedef unsigned uv4 __attribute__((ext_vector_type(4)));
typedef int      iv4 __attribute__((ext_vector_type(4)));

// ---------- pass 1: per-chunk histogram + direct scatter into per-bucket global regions ----------
// word = (src << 7) | (dst & 127); region base for bucket b is b*MCAP, cursor via global atomic.

__global__ __launch_bounds__(512) void k_bin(const int* __restrict__ src,
                                             const int* __restrict__ dst,
                                             unsigned* __restrict__ gcur,
                                             unsigned* __restrict__ regions) {
    __shared__ unsigned h[NB];
    int tid = threadIdx.x;
    int c = blockIdx.x;
    int b0 = c * CHUNK_S;
    int e1 = min(b0 + CHUNK_S, NE);

    for (int j = tid; j < NB; j += 512) h[j] = 0;
    __syncthreads();

    iv4 dreg[4], sreg[4];
    int nit = 0;
    for (int v = b0 + tid * 4; v + 3 < e1; v += 2048) {
        iv4 d4 = *(const iv4*)(dst + v);
        iv4 s4 = *(const iv4*)(src + v);
        dreg[nit] = d4; sreg[nit] = s4; ++nit;
        atomicAdd(&h[((unsigned)d4.x) >> BKT_BITS], 1u);
        atomicAdd(&h[((unsigned)d4.y) >> BKT_BITS], 1u);
        atomicAdd(&h[((unsigned)d4.z) >> BKT_BITS], 1u);
        atomicAdd(&h[((unsigned)d4.w) >> BKT_BITS], 1u);
    }
    __syncthreads();

    // claim a contiguous run in each touched bucket's region; h[b] becomes global write cursor
    for (int j = tid; j < NB; j += 512) {
        unsigned cEdges = h[j];
        if (cEdges) h[j] = (unsigned)j * MCAP + atomicAdd(&gcur[j], cEdges);
    }
    __syncthreads();

    int it = 0;
    for (int v = b0 + tid * 4; v + 3 < e1; v += 2048, ++it) {
        iv4 d4 = dreg[it];
        iv4 s4 = sreg[it];
        {   unsigned d = (unsigned)d4.x, s = (unsigned)s4.x;
            unsigned pos = atomicAdd(&h[d >> BKT_BITS], 1u);
            regions[pos] = (s << BKT_BITS) | (d & (BKT_NODES - 1)); }
        {   unsigned d = (unsigned)d4.y, s = (unsigned)s4.y;
            unsigned pos = atomicAdd(&h[d >> BKT_BITS], 1u);
            regions[pos] = (s << BKT_BITS) | (d & (BKT_NODES - 1)); }
        {   unsigned d = (unsigned)d4.z, s = (unsigned)s4.z;
            unsigned pos = atomicAdd(&h[d >> BKT_BITS], 1u);
            regions[pos] = (s << BKT_BITS) | (d & (BKT_NODES - 1)); }
        {   unsigned d = (unsigned)d4.w, s = (unsigned)s4.w;
            unsigned pos = atomicAdd(&h[d >> BKT_BITS], 1u);
            regions[pos] = (s << BKT_BITS) | (d & (BKT_NODES - 1)); }
    }
}

// ---------- pass 2: per-bucket degree count -> dinv, p ----------

__global__ __launch_bounds__(256) void k_deg(const unsigned* __restrict__ regions,
                                             const unsigned* __restrict__ gcur,
                                             const float* __restrict__ x,
                                             float* __restrict__ dinv,
                                             float* __restrict__ p) {
    __shared__ unsigned cnt[BKT_NODES];
    int tid = threadIdx.x, b = blockIdx.x;
    if (tid < BKT_NODES) cnt[tid] = 0;
    __syncthreads();

    unsigned sz = gcur[b];
    const unsigned* r = regions + (size_t)b * MCAP;
    unsigned sz4 = sz & ~3u;
    for (unsigned j = (unsigned)tid * 4; j < sz4; j += 1024) {
        uv4 e = *(const uv4*)(r + j);
        atomicAdd(&cnt[e.x & (BKT_NODES - 1)], 1u);
        atomicAdd(&cnt[e.y & (BKT_NODES - 1)], 1u);
        atomicAdd(&cnt[e.z & (BKT_NODES - 1)], 1u);
        atomicAdd(&cnt[e.w & (BKT_NODES - 1)], 1u);
    }
    for (unsigned j = sz4 + (unsigned)tid; j < sz; j += 256)
        atomicAdd(&cnt[r[j] & (BKT_NODES - 1)], 1u);
    __syncthreads();

    if (tid < BKT_NODES) {
        int node = b * BKT_NODES + tid;
        if (node < NN) {
            float di = rsqrtf((float)(cnt[tid] + 1u));   // +1 self-loop
            dinv[node] = di;
            p[node] = di * x[node];
        }
    }
}

// ---------- pass 3: layer-1 aggregation via LDS float atomics + fused MLP ----------

__global__ __launch_bounds__(256) void k_agg1(const unsigned* __restrict__ regions,
                                              const unsigned* __restrict__ gcur,
                                              const float* __restrict__ dinv,
                                              const float* __restrict__ p,
                                              const float* __restrict__ W1,
                                              const float* __restrict__ b1,
                                              const float* __restrict__ W2,
                                              float2* __restrict__ g) {
    __shared__ float acc[BKT_NODES];
    int tid = threadIdx.x, b = blockIdx.x;
    if (tid < BKT_NODES) acc[tid] = 0.f;
    __syncthreads();

    unsigned sz = gcur[b];
    const unsigned* r = regions + (size_t)b * MCAP;
    unsigned sz4 = sz & ~3u;
    for (unsigned j = (unsigned)tid * 4; j < sz4; j += 1024) {
        uv4 e = *(const uv4*)(r + j);
        float p0 = p[e.x >> BKT_BITS];
        float p1 = p[e.y >> BKT_BITS];
        float p2 = p[e.z >> BKT_BITS];
        float p3 = p[e.w >> BKT_BITS];
        atomicAdd(&acc[e.x & (BKT_NODES - 1)], p0);
        atomicAdd(&acc[e.y & (BKT_NODES - 1)], p1);
        atomicAdd(&acc[e.z & (BKT_NODES - 1)], p2);
        atomicAdd(&acc[e.w & (BKT_NODES - 1)], p3);
    }
    for (unsigned j = sz4 + (unsigned)tid; j < sz; j += 256) {
        unsigned e = r[j];
        atomicAdd(&acc[e & (BKT_NODES - 1)], p[e >> BKT_BITS]);
    }
    __syncthreads();

    if (tid < BKT_NODES) {
        int node = b * BKT_NODES + tid;
        if (node < NN) {
            float di = dinv[node];
            float sf = di * (acc[tid] + p[node]);        // + self-loop
            float g0 = 0.f, g1 = 0.f;
#pragma unroll
            for (int c = 0; c < HC; ++c) {
                float h = fmaxf(fmaf(sf, W1[c], b1[c]), 0.f);
                g0 = fmaf(h, W2[2 * c], g0);
                g1 = fmaf(h, W2[2 * c + 1], g1);
            }
            g[node] = make_float2(di * g0, di * g1);
        }
    }
}

// ---------- pass 4: layer-2 aggregation (float2) ----------

__global__ __launch_bounds__(256) void k_agg2(const unsigned* __restrict__ regions,
                                              const unsigned* __restrict__ gcur,
                                              const float* __restrict__ dinv,
                                              const float2* __restrict__ g,
                                              const float* __restrict__ b2,
                                              float2* __restrict__ out) {
    __shared__ float accx[BKT_NODES];
    __shared__ float accy[BKT_NODES];
    int tid = threadIdx.x, b = blockIdx.x;
    if (tid < BKT_NODES) { accx[tid] = 0.f; accy[tid] = 0.f; }
    __syncthreads();

    unsigned sz = gcur[b];
    const unsigned* r = regions + (size_t)b * MCAP;
    unsigned sz4 = sz & ~3u;
    for (unsigned j = (unsigned)tid * 4; j < sz4; j += 1024) {
        uv4 e = *(const uv4*)(r + j);
        float2 v0 = g[e.x >> BKT_BITS];
        float2 v1 = g[e.y >> BKT_BITS];
        float2 v2 = g[e.z >> BKT_BITS];
        float2 v3 = g[e.w >> BKT_BITS];
        atomicAdd(&accx[e.x & (BKT_NODES - 1)], v0.x);
        atomicAdd(&accy[e.x & (BKT_NODES - 1)], v0.y);
        atomicAdd(&accx[e.y & (BKT_NODES - 1)], v1.x);
        atomicAdd(&accy[e.y & (BKT_NODES - 1)], v1.y);
        atomicAdd(&accx[e.z & (BKT_NODES - 1)], v2.x);
        atomicAdd(&accy[e.z & (BKT_NODES - 1)], v2.y);
        atomicAdd(&accx[e.w & (BKT_NODES - 1)], v3.x);
        atomicAdd(&accy[e.w & (BKT_NODES - 1)], v3.y);
    }
    for (unsigned j = sz4 + (unsigned)tid; j < sz; j += 256) {
        unsigned e = r[j];
        float2 v = g[e >> BKT_BITS];
        atomicAdd(&accx[e & (BKT_NODES - 1)], v.x);
        atomicAdd(&accy[e & (BKT_NODES - 1)], v.y);
    }
    __syncthreads();

    if (tid < BKT_NODES) {
        int node = b * BKT_NODES + tid;
        if (node < NN) {
            float di = dinv[node];
            float2 me = g[node];
            float ax = accx[tid] + me.x;                 // + self-loop
            float ay = accy[tid] + me.y;
            out[node] = make_float2(fmaf(di, ax, b2[0]), fmaf(di, ay, b2[1]));
        }
    }
}

// ---------- fallback: atomic-scatter path (small ws) ----------

__global__ __launch_bounds__(256) void f_deg(const int* __restrict__ dst,
                                             unsigned int* __restrict__ deg, int E) {
    int i = blockIdx.x * blockDim.x + threadIdx.x;
    if (i < E) atomicAdd(&deg[dst[i]], 1u);
}
__global__ __launch_bounds__(256) void f_node1(const float* __restrict__ x,
                                               const unsigned int* __restrict__ deg,
                                               float* __restrict__ dinv, float* __restrict__ p,
                                               float* __restrict__ t, int N) {
    int i = blockIdx.x * blockDim.x + threadIdx.x;
    if (i < N) {
        float di = rsqrtf((float)(deg[i] + 1u));
        dinv[i] = di; float pi = di * x[i]; p[i] = pi; t[i] = pi;
    }
}
__global__ __launch_bounds__(256) void f_scatter1(const int* __restrict__ src,
                                                  const int* __restrict__ dst,
                                                  const float* __restrict__ p,
                                                  float* __restrict__ t, int E) {
    int i = blockIdx.x * blockDim.x + threadIdx.x;
    if (i < E) atomicAdd(&t[dst[i]], p[src[i]]);
}
__global__ __launch_bounds__(256) void f_node2(const float* __restrict__ dinv,
                                               const float* __restrict__ t,
                                               const float* __restrict__ W1,
                                               const float* __restrict__ b1,
                                               const float* __restrict__ W2,
                                               float2* __restrict__ g,
                                               float2* __restrict__ acc, int N) {
    int i = blockIdx.x * blockDim.x + threadIdx.x;
    if (i < N) {
        float di = dinv[i]; float s = di * t[i];
        float g0 = 0.f, g1 = 0.f;
#pragma unroll
        for (int c = 0; c < HC; ++c) {
            float h = fmaxf(fmaf(s, W1[c], b1[c]), 0.f);
            g0 = fmaf(h, W2[2 * c], g0); g1 = fmaf(h, W2[2 * c + 1], g1);
        }
        float2 gv = make_float2(di * g0, di * g1);
        g[i] = gv; acc[i] = gv;
    }
}
__global__ __launch_bounds__(256) void f_scatter2(const int* __restrict__ src,
                                                  const int* __restrict__ dst,
                                                  const float2* __restrict__ g,
                                                  float* __restrict__ acc, int E) {
    int i = blockIdx.x * blockDim.x + threadIdx.x;
    if (i < E) {
        int s = src[i], d = dst[i];
        float2 gv = g[s];
        atomicAdd(&acc[2 * d], gv.x);
        atomicAdd(&acc[2 * d + 1], gv.y);
    }
}
__global__ __launch_bounds__(256) void f_out(const float* __restrict__ dinv,
                                             const float* __restrict__ b2,
                                             float* __restrict__ out, int N) {
    int i = blockIdx.x * blockDim.x + threadIdx.x;
    if (i < N) {
        float di = dinv[i];
        out[2 * i]     = fmaf(di, out[2 * i],     b2[0]);
        out[2 * i + 1] = fmaf(di, out[2 * i + 1], b2[1]);
    }
}

extern "C" void kernel_launch(void* const* d_in, const int* in_sizes, int n_in,
                              void* d_out, int out_size, void* d_ws, size_t ws_size,
                              hipStream_t stream) {
    const float* x  = (const float*)d_in[0];
    const int* ei   = (const int*)d_in[1];
    const int* src  = ei;
    const int* dst  = ei + NE;
    const float* W1 = (const float*)d_in[2];
    const float* b1 = (const float*)d_in[3];
    const float* W2 = (const float*)d_in[4];
    const float* b2 = (const float*)d_in[5];

    const int BT = 256;
    const int gridE = (NE + BT - 1) / BT;
    const int gridN = (NN + BT - 1) / BT;

    size_t need = 0;
    auto carve = [&](size_t bytes) { size_t o = need; need += (bytes + 255) & ~(size_t)255; return o; };
    size_t o_gcur = carve((size_t)NB * 4);
    size_t o_dinv = carve((size_t)NN * 4);
    size_t o_p    = carve((size_t)NN * 4);
    size_t o_g    = carve((size_t)NN * 8);
    size_t o_reg  = carve((size_t)NB * MCAP * 4);

    if (ws_size >= need) {
        char* ws = (char*)d_ws;
        unsigned* gcur   = (unsigned*)(ws + o_gcur);
        float*    dinv   = (float*)(ws + o_dinv);
        float*    p      = (float*)(ws + o_p);
        float2*   g      = (float2*)(ws + o_g);
        unsigned* regions= (unsigned*)(ws + o_reg);

        hipMemsetAsync(gcur, 0, (size_t)NB * 4, stream);
        k_bin <<<NCH, 512, 0, stream>>>(src, dst, gcur, regions);
        k_deg <<<NB, 256, 0, stream>>>(regions, gcur, x, dinv, p);
        k_agg1<<<NB, 256, 0, stream>>>(regions, gcur, dinv, p, W1, b1, W2, g);
        k_agg2<<<NB, 256, 0, stream>>>(regions, gcur, dinv, g, b2, (float2*)d_out);
    } else {
        float* out = (float*)d_out;
        char* ws = (char*)d_ws;
        unsigned int* deg = (unsigned int*)ws;
        float* dinv = (float*)(ws + 1 * sizeof(float) * NN);
        float* p    = (float*)(ws + 2 * sizeof(float) * NN);
        float* t    = (float*)(ws + 3 * sizeof(float) * NN);
        float2* g   = (float2*)(ws + 4 * sizeof(float) * NN);

        hipMemsetAsync(deg, 0, NN * sizeof(unsigned int), stream);
        f_deg<<<gridE, BT, 0, stream>>>(dst, deg, NE);
        f_node1<<<gridN, BT, 0, stream>>>(x, deg, dinv, p, t, NN);
        f_scatter1<<<gridE, BT, 0, stream>>>(src, dst, p, t, NE);
        f_node2<<<gridN, BT, 0, stream>>>(dinv, t, W1, b1, W2, g, (float2*)out, NN);
        f_scatter2<<<gridE, BT, 0, stream>>>(src, dst, g, out, NE);
        f_out<<<gridN, BT, 0, stream>>>(dinv, b2, out, NN);
    }
}